// Round 6
// baseline (233.429 us; speedup 1.0000x reference)
//
#include <hip/hip_runtime.h>
#include <stdint.h>
#include <math.h>

// x[B,M,D] fp32, center[M,K,D] fp32
#define B_TOT 16384
#define M_TOT 16
#define K_TOT 256
#define D_TOT 64
#define ROWS_PB 512
#define THREADS 512
#define NCHUNK (B_TOT / ROWS_PB)  // 32 -> grid 512 (2 blocks/CU, fully resident)
#define CAP 3072                  // candidate list capacity (12 KB)
// a-space half-window: |a_mfma - 0.5*exact_am| per k <= 7.84e-3*||x||*||c_k||;
// need Wa >= 0.5*(err_k + err_k*) -> Wa = XERRF*||x||*cmax + SLACK/2 (R5-proven).
#define XERRF 0.0160f   // 2*7.84e-3 (bf16 RNE per operand) with fp32-accum margin
#define SLACK 5.0e-5f   // fp32 final-add / sqrt-rounding tie-merge window

typedef unsigned long long ull;
typedef __attribute__((ext_vector_type(8))) short short8;   // 8 bf16 (4 VGPRs)
typedef __attribute__((ext_vector_type(4))) float f32x4;
typedef __attribute__((ext_vector_type(4))) uint32_t u32x4;

// Order-preserving float->uint map
__device__ __forceinline__ uint32_t f32_key(float f) {
  uint32_t u = __float_as_uint(f);
  return (u & 0x80000000u) ? ~u : (u | 0x80000000u);
}
__device__ __forceinline__ ull u64min(ull a, ull b) { return a < b ? a : b; }

// fp32 -> bf16 round-to-nearest-even (int trick; no inf/nan in data)
__device__ __forceinline__ uint32_t bf16rne(float f) {
  uint32_t u = __float_as_uint(f);
  return (u + 0x7FFFu + ((u >> 16) & 1u)) >> 16;
}
__device__ __forceinline__ uint32_t pack2(float a, float b) {
  return bf16rne(a) | (bf16rne(b) << 16);
}
// fp32 -> bf16 rounded toward +inf (result as bf16 >= input): safe tile-keep
__device__ __forceinline__ uint32_t bf16up(float f) {
  uint32_t u = __float_as_uint(f);
  return (((int)u >= 0) ? (u + 0xFFFFu) : u) >> 16;
}

// LDS byte offset for (row, 16B-chunk c) with XOR swizzle (involution)
__device__ __forceinline__ int swz(int row, int c) {
  return row * 128 + ((c * 16) ^ ((row & 7) << 4));
}

// Streaming XLA-CPU lane-16 tree horizontal part (bit-exact association)
__device__ __forceinline__ float xla_hsum16(const float* r) {
#pragma clang fp contract(off)
#pragma clang fp reassociate(off)
  float u[8];
#pragma unroll
  for (int q = 0; q < 8; ++q) u[q] = r[q] + r[q + 8];
  float v[4];
#pragma unroll
  for (int q = 0; q < 4; ++q) v[q] = u[q] + u[q + 4];
  float w0 = v[0] + v[2];
  float w1 = v[1] + v[3];
  return w0 + w1;
}

// Exact XLA-emulating (key<<32)|k. Bit-identical math to the R1-R5 kernels
// that passed with absmax 0 (SSE 4-accumulator mul+add chain, jax source-order
// final ops, correctly-rounded f32 sqrt via f64).
__device__ __forceinline__ ull exact_key_stream(int k, const float* __restrict__ xrow,
                                                const float* __restrict__ crow,
                                                float csq, float x_sq) {
#pragma clang fp contract(off)
#pragma clang fp reassociate(off)
  const float4* cp = reinterpret_cast<const float4*>(crow);
  const float4* xp = reinterpret_cast<const float4*>(xrow);
  float a[4] = {0.f, 0.f, 0.f, 0.f};
#pragma unroll
  for (int it = 0; it < 4; ++it) {
    float cc[16], xx[16];
#pragma unroll
    for (int q = 0; q < 4; ++q) {
      float4 v = cp[4 * it + q];
      cc[4 * q + 0] = v.x; cc[4 * q + 1] = v.y;
      cc[4 * q + 2] = v.z; cc[4 * q + 3] = v.w;
      float4 w = xp[4 * it + q];
      xx[4 * q + 0] = w.x; xx[4 * q + 1] = w.y;
      xx[4 * q + 2] = w.z; xx[4 * q + 3] = w.w;
    }
#pragma unroll
    for (int L = 0; L < 4; ++L) {
      float m3 = cc[12 + L] * xx[12 + L];
      float s3 = m3 + a[L];
      float m2 = cc[8 + L] * xx[8 + L];
      float s2 = m2 + s3;
      float m1 = cc[4 + L] * xx[4 + L];
      float s1 = m1 + s2;
      float m0 = cc[0 + L] * xx[0 + L];
      a[L] = m0 + s1;
    }
  }
  const float dot = (a[0] + a[1]) + (a[2] + a[3]);
  const float two_dot = 2.0f * dot;               // exact
  const float d2 = (csq - two_dot) + x_sq;        // jax/XLA source order
  const float s = (float)sqrt((double)d2);        // correctly-rounded f32 sqrt
  return (((ull)f32_key(s)) << 32) | (unsigned)k; // ties -> lowest k
}

// 512 threads, 512 rows. t<256 stage centers (bf16 LDS + csq). Every thread:
// own-row xsq, B-fragments packed in-register from global x (no x-LDS).
// Single MFMA scan (C-in = -csq/2, argmax a) with tile-relative creep-free
// marks + packed-bf16 tile maxima; push filtered marks; bit-exact verify.
__global__ __launch_bounds__(THREADS, 2) void mkmeans_fwd(
    const float* __restrict__ x, const float* __restrict__ center,
    float* __restrict__ recon, float* __restrict__ outC, float* __restrict__ outL)
{
#pragma clang fp contract(off)
#pragma clang fp reassociate(off)
  __shared__ __align__(16) char s_cb[K_TOT * 128];    // bf16 center rows, swizzled
  __shared__ __align__(16) float s_csq[K_TOT];        // exact c_sq (verify)
  __shared__ __align__(16) float s_nch[K_TOT];        // -0.5f*c_sq (MFMA C-in)
  __shared__ float s_xsq[ROWS_PB];                    // exact x_sq
  __shared__ float s_xnorm[ROWS_PB];                  // upper-bound ||x||
  __shared__ float s_cmaxw[4];                        // per-wave max ||c||
  __shared__ ull s_best[ROWS_PB];
  __shared__ uint32_t s_list[CAP];                    // (row<<16)|k
  __shared__ int s_nc, s_ovf;

  const int t = threadIdx.x;
  const int l = t & 63;
  const int wv = t >> 6;
  const int g = l >> 4;          // lane group 0..3 (k sub-block)
  const int j = l & 15;          // MFMA column
  const int bi = blockIdx.x;
  const int m = bi & (M_TOT - 1);
  const int chunk = bi >> 4;
  const int b0 = chunk * ROWS_PB;

  const float* cmbase = center + (size_t)m * (K_TOT * D_TOT);

  if (t == 0) { s_nc = 0; s_ovf = 0; }
  s_best[t] = ~0ull;

  // ---- center staging: t<256 stages center row t (streaming, verbatim bits) ----
  if (t < K_TOT) {
    const float4* cp = reinterpret_cast<const float4*>(cmbase + (size_t)t * D_TOT);
    float4* dst = (chunk == 0)
        ? reinterpret_cast<float4*>(outC + (size_t)m * (K_TOT * D_TOT) + (size_t)t * D_TOT)
        : nullptr;
    float r[16];
#pragma unroll
    for (int mm = 0; mm < 4; ++mm) {
      float q[16];
#pragma unroll
      for (int qq = 0; qq < 4; ++qq) {
        float4 v = cp[4 * mm + qq];
        if (dst) dst[4 * mm + qq] = v;   // verbatim passthrough
        q[4 * qq + 0] = v.x; q[4 * qq + 1] = v.y;
        q[4 * qq + 2] = v.z; q[4 * qq + 3] = v.w;
      }
#pragma unroll
      for (int jj = 0; jj < 16; ++jj) {
        const float p = q[jj] * q[jj];
        r[jj] = (mm == 0) ? p : (r[jj] + p);
      }
#pragma unroll
      for (int h = 0; h < 2; ++h) {
        u32x4 u = {pack2(q[8 * h + 0], q[8 * h + 1]),
                   pack2(q[8 * h + 2], q[8 * h + 3]),
                   pack2(q[8 * h + 4], q[8 * h + 5]),
                   pack2(q[8 * h + 6], q[8 * h + 7])};
        *reinterpret_cast<u32x4*>(s_cb + swz(t, 2 * mm + h)) = u;
      }
    }
    const float csq = xla_hsum16(r);
    s_csq[t] = csq;
    s_nch[t] = -0.5f * csq;             // exact
    float cs = sqrtf(csq) * 1.00001f + 1e-12f;
#pragma unroll
    for (int off = 1; off < 64; off <<= 1)
      cs = fmaxf(cs, __shfl_xor(cs, off, 64));
    if (l == 0) s_cmaxw[wv] = cs;
  }

  // ---- exact x_sq for own row t (streaming XLA tree, exact bits) ----
  {
    const float4* xp = reinterpret_cast<const float4*>(
        x + ((size_t)((b0 + t) * M_TOT + m)) * D_TOT);
    float r[16];
#pragma unroll
    for (int mm = 0; mm < 4; ++mm) {
      float q[16];
#pragma unroll
      for (int qq = 0; qq < 4; ++qq) {
        float4 v = xp[4 * mm + qq];
        q[4 * qq + 0] = v.x; q[4 * qq + 1] = v.y;
        q[4 * qq + 2] = v.z; q[4 * qq + 3] = v.w;
      }
#pragma unroll
      for (int jj = 0; jj < 16; ++jj) {
        const float p = q[jj] * q[jj];
        r[jj] = (mm == 0) ? p : (r[jj] + p);
      }
    }
    const float xsq = xla_hsum16(r);
    s_xsq[t] = xsq;
    s_xnorm[t] = sqrtf(xsq) * 1.00001f + 1e-12f;
  }

  // ---- B fragments: packed in-register from global x (x-LDS eliminated) ----
  short8 bfr[4][2];
#pragma unroll
  for (int rg = 0; rg < 4; ++rg) {
    const int row = wv * 64 + rg * 16 + j;
    const float4* xr4 = reinterpret_cast<const float4*>(
        x + ((size_t)((b0 + row) * M_TOT + m)) * D_TOT);
#pragma unroll
    for (int ks = 0; ks < 2; ++ks) {
      const int c = ks * 4 + g;               // 8-float chunk: d = [8c, 8c+8)
      const float4 f0 = xr4[2 * c];
      const float4 f1 = xr4[2 * c + 1];
      u32x4 u = {pack2(f0.x, f0.y), pack2(f0.z, f0.w),
                 pack2(f1.x, f1.y), pack2(f1.z, f1.w)};
      bfr[rg][ks] = *reinterpret_cast<short8*>(&u);
    }
  }
  __syncthreads();

  // ---- per-rg a-space half-window ----
  const float cmax = fmaxf(fmaxf(s_cmaxw[0], s_cmaxw[1]),
                           fmaxf(s_cmaxw[2], s_cmaxw[3]));
  float Wa[4];
#pragma unroll
  for (int rg = 0; rg < 4; ++rg)
    Wa[rg] = XERRF * s_xnorm[wv * 64 + rg * 16 + j] * cmax + 0.5f * SLACK;

  // ---- single scan: a = dot - csq/2; tile-relative marks (creep-free) ----
  float m1[4] = {-3.0e38f, -3.0e38f, -3.0e38f, -3.0e38f};
  ull mk[4] = {0ull, 0ull, 0ull, 0ull};
  uint32_t tb[4][8];          // per-tile max, round-up bf16, 2 tiles per u32
#pragma unroll
  for (int T = 0; T < 16; ++T) {
    const short8 af0 = *reinterpret_cast<const short8*>(s_cb + swz(T * 16 + j, g));
    const short8 af1 = *reinterpret_cast<const short8*>(s_cb + swz(T * 16 + j, 4 + g));
    const f32x4 nch = *reinterpret_cast<const f32x4*>(&s_nch[T * 16 + g * 4]);
#pragma unroll
    for (int rg = 0; rg < 4; ++rg) {
      f32x4 a = __builtin_amdgcn_mfma_f32_16x16x32_bf16(af0, bfr[rg][0], nch, 0, 0, 0);
      a = __builtin_amdgcn_mfma_f32_16x16x32_bf16(af1, bfr[rg][1], a, 0, 0, 0);
      const float tmax = fmaxf(fmaxf(a[0], a[1]), fmaxf(a[2], a[3]));
      const float thr = tmax - Wa[rg];            // tile-relative: no creep
      uint32_t bits = 0u;
      bits |= (a[0] >= thr) ? 1u : 0u;
      bits |= (a[1] >= thr) ? 2u : 0u;
      bits |= (a[2] >= thr) ? 4u : 0u;
      bits |= (a[3] >= thr) ? 8u : 0u;
      mk[rg] |= ((ull)bits) << (4 * T);
      m1[rg] = fmaxf(m1[rg], tmax);
      const uint32_t h = bf16up(tmax);            // >= tmax (round toward +inf)
      if (T & 1) tb[rg][T >> 1] |= h << 16; else tb[rg][T >> 1] = h;
    }
  }

  // ---- push: row max via cross-g shuffles, tile filter, drain marks ----
#pragma unroll
  for (int rg = 0; rg < 4; ++rg) {
    float v = m1[rg];
    v = fmaxf(v, __shfl_xor(v, 16, 64));
    v = fmaxf(v, __shfl_xor(v, 32, 64));
    const float cut = v - Wa[rg];
    const int row = wv * 64 + rg * 16 + j;
#pragma unroll
    for (int T = 0; T < 16; ++T) {
      const uint32_t h = (tb[rg][T >> 1] >> ((T & 1) * 16)) & 0xFFFFu;
      const float tmaxbf = __uint_as_float(h << 16);
      if (tmaxbf >= cut) {                        // superset keep (bf16up >= tmax)
        uint32_t bits = (uint32_t)((mk[rg] >> (4 * T)) & 0xFull);
        while (bits) {
          const int i = __builtin_ctz(bits);
          bits &= bits - 1;
          const int k = T * 16 + g * 4 + i;
          const int idx = atomicAdd(&s_nc, 1);
          if (idx < CAP)
            s_list[idx] = ((uint32_t)row << 16) | (uint32_t)k;
          else
            s_ovf = 1;
        }
      }
    }
  }
  __syncthreads();

  // ---- Verify: balanced drain of the candidate list (bit-exact) ----
  if (!s_ovf) {
    const int n = s_nc;
#pragma unroll 1
    for (int i = t; i < n; i += THREADS) {
      const uint32_t e = s_list[i];
      const int row = (int)(e >> 16);
      const int k = (int)(e & 0xffffu);
      const float* xrow = x + ((size_t)((b0 + row) * M_TOT + m)) * D_TOT;
      const float* crow = cmbase + (size_t)k * D_TOT;
      const ull key = exact_key_stream(k, xrow, crow, s_csq[k], s_xsq[row]);
      atomicMin(&s_best[row], key);
    }
  } else {
    // overflow fallback (never expected): brute-force row t over all k
    const float* xrow = x + ((size_t)((b0 + t) * M_TOT + m)) * D_TOT;
    ull best = ~0ull;
#pragma unroll 1
    for (int k = 0; k < K_TOT; ++k)
      best = u64min(best, exact_key_stream(k, xrow, cmbase + (size_t)k * D_TOT,
                                           s_csq[k], s_xsq[t]));
    s_best[t] = best;
  }
  __syncthreads();

  // ---- Outputs ----
  outL[(size_t)(b0 + t) * M_TOT + m] = (float)(uint32_t)(s_best[t] & 0xffffffffull);

  // recon: cooperative, 16 lanes per row -> 256B-contiguous loads and stores
  const float4* cm4 = reinterpret_cast<const float4*>(cmbase);
  float4* rec4 = reinterpret_cast<float4*>(recon);
#pragma unroll
  for (int it = 0; it < (ROWS_PB * 16) / THREADS; ++it) {
    const int slot = it * THREADS + t;
    const int row = slot >> 4, ch = slot & 15;
    const int kst = (int)(s_best[row] & 0xffffffffull);
    rec4[((size_t)((b0 + row) * M_TOT + m)) * 16 + ch] = cm4[kst * 16 + ch];  // verbatim
  }
}

extern "C" void kernel_launch(void* const* d_in, const int* in_sizes, int n_in,
                              void* d_out, int out_size, void* d_ws, size_t ws_size,
                              hipStream_t stream) {
  const float* x = (const float*)d_in[0];
  const float* center = (const float*)d_in[1];
  float* recon = (float*)d_out;                         // [B,M,D]
  float* outC = recon + (size_t)B_TOT * M_TOT * D_TOT;  // [M,K,D]
  float* outL = outC + (size_t)M_TOT * K_TOT * D_TOT;   // [B,M,1]

  mkmeans_fwd<<<dim3(NCHUNK * M_TOT), dim3(THREADS), 0, stream>>>(x, center, recon, outC, outL);
}

// Round 7
// 175.600 us; speedup vs baseline: 1.3293x; 1.3293x over previous
//
#include <hip/hip_runtime.h>
#include <stdint.h>
#include <math.h>

// x[B,M,D] fp32, center[M,K,D] fp32
#define B_TOT 16384
#define M_TOT 16
#define K_TOT 256
#define D_TOT 64
#define ROWS_PB 256
#define THREADS 512
#define NCHUNK (B_TOT / ROWS_PB)  // 64 -> grid 1024
#define CAP 3072                  // candidate list capacity (12 KB)
// Mark window: |a_mfma - a_true| <= 2^-8 * ||x|| * ||c_k|| (bf16 RNE on both
// operands, Cauchy-Schwarz; fp32 accum ~1e-7 extra). Need to cover err_k +
// err_k*: thr_k = m1row - XS*||x||*(cmax + cs_k) - SLACK.  XS = 8e-3 is 2.05x
// the true 3.9e-3 bound; SLACK covers fp32-chain/sqrt tie windows (~7e-6).
#define XS 8.0e-3f
#define SLACK 5.0e-5f

typedef unsigned long long ull;
typedef __attribute__((ext_vector_type(8))) short short8;   // 8 bf16 (4 VGPRs)
typedef __attribute__((ext_vector_type(4))) float f32x4;
typedef __attribute__((ext_vector_type(4))) uint32_t u32x4;

// Order-preserving float->uint map
__device__ __forceinline__ uint32_t f32_key(float f) {
  uint32_t u = __float_as_uint(f);
  return (u & 0x80000000u) ? ~u : (u | 0x80000000u);
}
__device__ __forceinline__ ull u64min(ull a, ull b) { return a < b ? a : b; }

// fp32 -> bf16 round-to-nearest-even (int trick; no inf/nan in data)
__device__ __forceinline__ uint32_t bf16rne(float f) {
  uint32_t u = __float_as_uint(f);
  return (u + 0x7FFFu + ((u >> 16) & 1u)) >> 16;
}
__device__ __forceinline__ uint32_t pack2(float a, float b) {
  return bf16rne(a) | (bf16rne(b) << 16);
}

// LDS byte offset for (row, 16B-chunk c) with XOR swizzle (involution)
__device__ __forceinline__ int swz(int row, int c) {
  return row * 128 + ((c * 16) ^ ((row & 7) << 4));
}

// Streaming XLA-CPU lane-16 tree horizontal part (bit-exact association)
__device__ __forceinline__ float xla_hsum16(const float* r) {
#pragma clang fp contract(off)
#pragma clang fp reassociate(off)
  float u[8];
#pragma unroll
  for (int q = 0; q < 8; ++q) u[q] = r[q] + r[q + 8];
  float v[4];
#pragma unroll
  for (int q = 0; q < 4; ++q) v[q] = u[q] + u[q + 4];
  float w0 = v[0] + v[2];
  float w1 = v[1] + v[3];
  return w0 + w1;
}

// Exact XLA-emulating (key<<32)|k. Bit-identical math to the R1-R6 kernels
// that passed with absmax 0 (SSE 4-accumulator mul+add chain, jax source-order
// final ops, correctly-rounded f32 sqrt via f64).
__device__ __forceinline__ ull exact_key_stream(int k, const float* __restrict__ xrow,
                                                const float* __restrict__ crow,
                                                float csq, float x_sq) {
#pragma clang fp contract(off)
#pragma clang fp reassociate(off)
  const float4* cp = reinterpret_cast<const float4*>(crow);
  const float4* xp = reinterpret_cast<const float4*>(xrow);
  float a[4] = {0.f, 0.f, 0.f, 0.f};
#pragma unroll
  for (int it = 0; it < 4; ++it) {
    float cc[16], xx[16];
#pragma unroll
    for (int q = 0; q < 4; ++q) {
      float4 v = cp[4 * it + q];
      cc[4 * q + 0] = v.x; cc[4 * q + 1] = v.y;
      cc[4 * q + 2] = v.z; cc[4 * q + 3] = v.w;
      float4 w = xp[4 * it + q];
      xx[4 * q + 0] = w.x; xx[4 * q + 1] = w.y;
      xx[4 * q + 2] = w.z; xx[4 * q + 3] = w.w;
    }
#pragma unroll
    for (int L = 0; L < 4; ++L) {
      float m3 = cc[12 + L] * xx[12 + L];
      float s3 = m3 + a[L];
      float m2 = cc[8 + L] * xx[8 + L];
      float s2 = m2 + s3;
      float m1 = cc[4 + L] * xx[4 + L];
      float s1 = m1 + s2;
      float m0 = cc[0 + L] * xx[0 + L];
      a[L] = m0 + s1;
    }
  }
  const float dot = (a[0] + a[1]) + (a[2] + a[3]);
  const float two_dot = 2.0f * dot;               // exact
  const float d2 = (csq - two_dot) + x_sq;        // jax/XLA source order
  const float s = (float)sqrt((double)d2);        // correctly-rounded f32 sqrt
  return (((ull)f32_key(s)) << 32) | (unsigned)k; // ties -> lowest k
}

// 512 threads, 256 rows. t<256: exact xsq for row t. t>=256: stage center row
// (bf16 LDS + exact csq + cmax + outC). B-frags packed in registers from
// global x (no x-LDS; rg=2 keeps state at 16 VGPRs -> no spill). Scan A:
// MFMA (C-in = -csq/2) running max. Scan B: bit-identical recompute, mark
// a >= final-threshold (creep-free). Balanced bit-exact verify; coalesced out.
__global__ __launch_bounds__(THREADS, 4) void mkmeans_fwd(
    const float* __restrict__ x, const float* __restrict__ center,
    float* __restrict__ recon, float* __restrict__ outC, float* __restrict__ outL)
{
#pragma clang fp contract(off)
#pragma clang fp reassociate(off)
  __shared__ __align__(16) char s_cb[K_TOT * 128];    // bf16 center rows, swizzled
  __shared__ __align__(16) float s_csq[K_TOT];        // exact c_sq (verify)
  __shared__ __align__(16) float s_nch[K_TOT];        // -0.5f*c_sq (MFMA C-in)
  __shared__ __align__(16) float s_csqrt[K_TOT];      // upper-bound ||c_k||
  __shared__ float s_xsq[ROWS_PB];                    // exact x_sq
  __shared__ float s_xnorm[ROWS_PB];                  // upper-bound ||x||
  __shared__ float s_cmaxw[4];                        // per-wave max ||c||
  __shared__ ull s_best[ROWS_PB];
  __shared__ uint32_t s_list[CAP];                    // (row<<16)|k
  __shared__ int s_nc, s_ovf;

  const int t = threadIdx.x;
  const int l = t & 63;
  const int wv = t >> 6;
  const int g = l >> 4;          // lane group 0..3 (k sub-block)
  const int j = l & 15;          // MFMA column
  const int bi = blockIdx.x;
  const int m = bi & (M_TOT - 1);
  const int chunk = bi >> 4;
  const int b0 = chunk * ROWS_PB;

  const float* cmbase = center + (size_t)m * (K_TOT * D_TOT);

  if (t == 0) { s_nc = 0; s_ovf = 0; }

  // ---- phase 0a: t<256 -> exact x_sq for row b0+t (streaming XLA tree) ----
  if (t < ROWS_PB) {
    const float4* xp = reinterpret_cast<const float4*>(
        x + ((size_t)((b0 + t) * M_TOT + m)) * D_TOT);
    float r[16];
#pragma unroll
    for (int mm = 0; mm < 4; ++mm) {
      float q[16];
#pragma unroll
      for (int qq = 0; qq < 4; ++qq) {
        float4 v = xp[4 * mm + qq];
        q[4 * qq + 0] = v.x; q[4 * qq + 1] = v.y;
        q[4 * qq + 2] = v.z; q[4 * qq + 3] = v.w;
      }
#pragma unroll
      for (int jj = 0; jj < 16; ++jj) {
        const float p = q[jj] * q[jj];
        r[jj] = (mm == 0) ? p : (r[jj] + p);
      }
    }
    const float xsq = xla_hsum16(r);
    s_xsq[t] = xsq;
    s_xnorm[t] = sqrtf(xsq) * 1.00001f + 1e-12f;
    s_best[t] = ~0ull;
  } else {
    // ---- phase 0b: t>=256 -> stage center row tc (verbatim bits) ----
    const int tc = t - ROWS_PB;
    const float4* cp = reinterpret_cast<const float4*>(cmbase + (size_t)tc * D_TOT);
    float4* dst = (chunk == 0)
        ? reinterpret_cast<float4*>(outC + (size_t)m * (K_TOT * D_TOT) + (size_t)tc * D_TOT)
        : nullptr;
    float r[16];
#pragma unroll
    for (int mm = 0; mm < 4; ++mm) {
      float q[16];
#pragma unroll
      for (int qq = 0; qq < 4; ++qq) {
        float4 v = cp[4 * mm + qq];
        if (dst) dst[4 * mm + qq] = v;   // verbatim passthrough
        q[4 * qq + 0] = v.x; q[4 * qq + 1] = v.y;
        q[4 * qq + 2] = v.z; q[4 * qq + 3] = v.w;
      }
#pragma unroll
      for (int jj = 0; jj < 16; ++jj) {
        const float p = q[jj] * q[jj];
        r[jj] = (mm == 0) ? p : (r[jj] + p);
      }
#pragma unroll
      for (int h = 0; h < 2; ++h) {
        u32x4 u = {pack2(q[8 * h + 0], q[8 * h + 1]),
                   pack2(q[8 * h + 2], q[8 * h + 3]),
                   pack2(q[8 * h + 4], q[8 * h + 5]),
                   pack2(q[8 * h + 6], q[8 * h + 7])};
        *reinterpret_cast<u32x4*>(s_cb + swz(tc, 2 * mm + h)) = u;
      }
    }
    const float csq = xla_hsum16(r);
    s_csq[tc] = csq;
    s_nch[tc] = -0.5f * csq;            // exact
    const float cs = sqrtf(csq) * 1.00001f + 1e-12f;
    s_csqrt[tc] = cs;
    float cw = cs;
#pragma unroll
    for (int off = 1; off < 64; off <<= 1)
      cw = fmaxf(cw, __shfl_xor(cw, off, 64));
    if (l == 0) s_cmaxw[wv - 4] = cw;
  }

  // ---- B fragments: packed in-register from global x (rg=2: 16 VGPRs) ----
  short8 bfr[2][2];
#pragma unroll
  for (int rg = 0; rg < 2; ++rg) {
    const int row = wv * 32 + rg * 16 + j;
    const float4* xr4 = reinterpret_cast<const float4*>(
        x + ((size_t)((b0 + row) * M_TOT + m)) * D_TOT);
#pragma unroll
    for (int ks = 0; ks < 2; ++ks) {
      const int c = ks * 4 + g;               // 8-float chunk: d = [8c, 8c+8)
      const float4 f0 = xr4[2 * c];
      const float4 f1 = xr4[2 * c + 1];
      u32x4 u = {pack2(f0.x, f0.y), pack2(f0.z, f0.w),
                 pack2(f1.x, f1.y), pack2(f1.z, f1.w)};
      bfr[rg][ks] = *reinterpret_cast<short8*>(&u);
    }
  }
  __syncthreads();

  // ---- Scan A: running max of a = dot - csq/2 ----
  float m1[2] = {-3.0e38f, -3.0e38f};
#pragma unroll
  for (int T = 0; T < 16; ++T) {
    const short8 af0 = *reinterpret_cast<const short8*>(s_cb + swz(T * 16 + j, g));
    const short8 af1 = *reinterpret_cast<const short8*>(s_cb + swz(T * 16 + j, 4 + g));
    const f32x4 nch = *reinterpret_cast<const f32x4*>(&s_nch[T * 16 + g * 4]);
#pragma unroll
    for (int rg = 0; rg < 2; ++rg) {
      f32x4 a = __builtin_amdgcn_mfma_f32_16x16x32_bf16(af0, bfr[rg][0], nch, 0, 0, 0);
      a = __builtin_amdgcn_mfma_f32_16x16x32_bf16(af1, bfr[rg][1], a, 0, 0, 0);
      m1[rg] = fmaxf(m1[rg], fmaxf(fmaxf(a[0], a[1]), fmaxf(a[2], a[3])));
    }
  }

  // ---- final thresholds (creep-free: computed AFTER the full scan) ----
  const float cmax = fmaxf(fmaxf(s_cmaxw[0], s_cmaxw[1]),
                           fmaxf(s_cmaxw[2], s_cmaxw[3]));
  float base[2], xw[2];
#pragma unroll
  for (int rg = 0; rg < 2; ++rg) {
    float v = m1[rg];
    v = fmaxf(v, __shfl_xor(v, 16, 64));
    v = fmaxf(v, __shfl_xor(v, 32, 64));          // row max over the 4 g-lanes
    xw[rg] = XS * s_xnorm[wv * 32 + rg * 16 + j];
    base[rg] = v - xw[rg] * cmax - SLACK;
  }

  // ---- Scan B: bit-identical recompute, mark a_k >= base - xw*cs_k ----
#pragma unroll
  for (int T = 0; T < 16; ++T) {
    const short8 af0 = *reinterpret_cast<const short8*>(s_cb + swz(T * 16 + j, g));
    const short8 af1 = *reinterpret_cast<const short8*>(s_cb + swz(T * 16 + j, 4 + g));
    const f32x4 nch = *reinterpret_cast<const f32x4*>(&s_nch[T * 16 + g * 4]);
    const f32x4 cs = *reinterpret_cast<const f32x4*>(&s_csqrt[T * 16 + g * 4]);
#pragma unroll
    for (int rg = 0; rg < 2; ++rg) {
      f32x4 a = __builtin_amdgcn_mfma_f32_16x16x32_bf16(af0, bfr[rg][0], nch, 0, 0, 0);
      a = __builtin_amdgcn_mfma_f32_16x16x32_bf16(af1, bfr[rg][1], a, 0, 0, 0);
      const int row = wv * 32 + rg * 16 + j;
#pragma unroll
      for (int i = 0; i < 4; ++i) {
        const float thr = fmaf(-xw[rg], cs[i], base[rg]);
        if (a[i] >= thr) {
          const int idx = atomicAdd(&s_nc, 1);
          if (idx < CAP)
            s_list[idx] = ((uint32_t)row << 16) | (uint32_t)(T * 16 + g * 4 + i);
          else
            s_ovf = 1;
        }
      }
    }
  }
  __syncthreads();

  // ---- Verify: balanced drain of the candidate list (bit-exact) ----
  if (!s_ovf) {
    const int n = s_nc;
#pragma unroll 1
    for (int i = t; i < n; i += THREADS) {
      const uint32_t e = s_list[i];
      const int row = (int)(e >> 16);
      const int k = (int)(e & 0xffffu);
      const float* xrow = x + ((size_t)((b0 + row) * M_TOT + m)) * D_TOT;
      const float* crow = cmbase + (size_t)k * D_TOT;
      const ull key = exact_key_stream(k, xrow, crow, s_csq[k], s_xsq[row]);
      atomicMin(&s_best[row], key);
    }
  } else if (t < ROWS_PB) {
    // overflow fallback (9x margin; never expected): brute-force row t
    const float* xrow = x + ((size_t)((b0 + t) * M_TOT + m)) * D_TOT;
    ull best = ~0ull;
#pragma unroll 1
    for (int k = 0; k < K_TOT; ++k)
      best = u64min(best, exact_key_stream(k, xrow, cmbase + (size_t)k * D_TOT,
                                           s_csq[k], s_xsq[t]));
    s_best[t] = best;
  }
  __syncthreads();

  // ---- Outputs ----
  if (t < ROWS_PB)
    outL[(size_t)(b0 + t) * M_TOT + m] = (float)(uint32_t)(s_best[t] & 0xffffffffull);

  // recon: cooperative, 16 lanes per row -> 256B-contiguous loads and stores
  const float4* cm4 = reinterpret_cast<const float4*>(cmbase);
  float4* rec4 = reinterpret_cast<float4*>(recon);
#pragma unroll
  for (int it = 0; it < (ROWS_PB * 16) / THREADS; ++it) {
    const int slot = it * THREADS + t;
    const int row = slot >> 4, ch = slot & 15;
    const int kst = (int)(s_best[row] & 0xffffffffull);
    rec4[((size_t)((b0 + row) * M_TOT + m)) * 16 + ch] = cm4[kst * 16 + ch];  // verbatim
  }
}

extern "C" void kernel_launch(void* const* d_in, const int* in_sizes, int n_in,
                              void* d_out, int out_size, void* d_ws, size_t ws_size,
                              hipStream_t stream) {
  const float* x = (const float*)d_in[0];
  const float* center = (const float*)d_in[1];
  float* recon = (float*)d_out;                         // [B,M,D]
  float* outC = recon + (size_t)B_TOT * M_TOT * D_TOT;  // [M,K,D]
  float* outL = outC + (size_t)M_TOT * K_TOT * D_TOT;   // [B,M,1]

  mkmeans_fwd<<<dim3(NCHUNK * M_TOT), dim3(THREADS), 0, stream>>>(x, center, recon, outC, outL);
}